// Round 4
// baseline (1051.330 us; speedup 1.0000x reference)
//
#include <hip/hip_runtime.h>

#define T_ 128
#define B_ 128
#define C_ 128
#define N_ 10
#define V_ 5
#define XROW 1280            // C_*N_ floats per (t,b)
#define ZROW 640             // C_*V_ per (t,b)
#define ZSTRIDE 81920        // B_*C_*V_ doubles per t
#define XSTRIDE 163840       // B_*C_*N_ floats per t

// ---------------------------------------------------------------------------
// Kernel 0: transpose fusion_w (128x256 fp32) -> WfT (256x128 fp32) in ws
// ---------------------------------------------------------------------------
__global__ __launch_bounds__(256) void k_twf(const float* __restrict__ Wf,
                                             float* __restrict__ WfT) {
  int i = blockIdx.x * 256 + threadIdx.x;   // 32768 total
  int c2 = i >> 7, o = i & 127;
  WfT[i] = Wf[o * 256 + c2];
}

// ---------------------------------------------------------------------------
// Kernel 1 (fused front): per (t,b): y = GN8(W1 @ x); z = GN1(Wf @ [y5|y5'])
// All math in fp64. Block = 512 threads = 2 pairs x (128 o x 2 halves).
// Grid = 8192 blocks (2 pairs each).
// ---------------------------------------------------------------------------
__global__ __launch_bounds__(512) void k_front(
    const float* __restrict__ x, const float* __restrict__ W1,
    const float* __restrict__ g1, const float* __restrict__ b1,
    const float* __restrict__ WfT, const float* __restrict__ fg,
    const float* __restrict__ fb, double* __restrict__ z_out)
{
  __shared__ float  w1t[128 * 129];     // [c][o], pad 129 -> conflict-free (66 KB)
  __shared__ float  xl[2 * XROW];       // 10 KB
  __shared__ double yl[2 * XROW];       // 20 KB
  __shared__ double zp[2 * ZROW];       // 10 KB (h=1 partials)
  __shared__ double redA[2][2][8][2];   // [pair][stat][group][nh]
  __shared__ double redB[2][2][2];      // [pair][stat][wave-half]

  const int tid = threadIdx.x;
  const int p   = tid >> 8;        // pair 0/1
  const int t8  = tid & 255;
  const int o   = t8 & 127;
  const int h   = t8 >> 7;         // n-half (phase A) / c2-half (phase B)
  const int lane = tid & 63;
  const size_t P0 = (size_t)blockIdx.x * 2;

  // stage W1 transposed (coalesced global reads; pad-129 kills write conflicts)
  for (int i = tid; i < 128 * 128; i += 512) {
    int oo = i >> 7, cc = i & 127;
    w1t[cc * 129 + oo] = W1[i];
  }
  // stage x rows for both pairs
  for (int i = tid; i < 2 * XROW; i += 512)
    xl[i] = x[P0 * XROW + i];
  __syncthreads();

  // ---- phase A: y[o][n], n in [5h, 5h+5) ----
  double acc[5] = {0.0, 0.0, 0.0, 0.0, 0.0};
  {
    const float* xp = &xl[p * XROW + 5 * h];
    for (int c = 0; c < 128; ++c) {
      double w = (double)w1t[c * 129 + o];
#pragma unroll
      for (int j = 0; j < 5; ++j)
        acc[j] = fma(w, (double)xp[c * 10 + j], acc[j]);
    }
  }
  // GN8: group g = o>>4 over (16 channels x 10) = 160 elems
  const int g = o >> 4;
  {
    double s = acc[0] + acc[1] + acc[2] + acc[3] + acc[4];
#pragma unroll
    for (int off = 1; off < 16; off <<= 1) s += __shfl_xor(s, off, 64);
    if ((o & 15) == 0) redA[p][0][g][h] = s;
  }
  __syncthreads();
  const double muA = (redA[p][0][g][0] + redA[p][0][g][1]) * (1.0 / 160.0);
  {
    double sq = 0.0;
#pragma unroll
    for (int j = 0; j < 5; ++j) { double d = acc[j] - muA; sq = fma(d, d, sq); }
#pragma unroll
    for (int off = 1; off < 16; off <<= 1) sq += __shfl_xor(sq, off, 64);
    if ((o & 15) == 0) redA[p][1][g][h] = sq;
  }
  __syncthreads();
  {
    const double rstdA =
        1.0 / sqrt((redA[p][1][g][0] + redA[p][1][g][1]) * (1.0 / 160.0) + 1e-5);
    const double gam = (double)g1[o], bet = (double)b1[o];
#pragma unroll
    for (int j = 0; j < 5; ++j)
      yl[p * XROW + o * 10 + 5 * h + j] = (acc[j] - muA) * rstdA * gam + bet;
  }
  __syncthreads();

  // ---- phase B: z[o][v] = sum_c Wf[o][c]*y[c][v] + Wf[o][c+128]*y[c][v+5] ----
  double accB[5] = {0.0, 0.0, 0.0, 0.0, 0.0};
  {
    const double* yp = &yl[p * XROW + 5 * h];   // h=1 -> columns v+5
    const float* wcol = WfT + (size_t)(h * 128) * 128 + o;  // WfT[(128h+c)][o]
    for (int c = 0; c < 128; ++c) {
      double w = (double)wcol[(size_t)c * 128];
#pragma unroll
      for (int j = 0; j < 5; ++j)
        accB[j] = fma(w, yp[c * 10 + j], accB[j]);
    }
  }
  if (h == 1) {
#pragma unroll
    for (int j = 0; j < 5; ++j) zp[p * ZROW + o * 5 + j] = accB[j];
  }
  __syncthreads();

  double zv[5];
  if (h == 0) {
#pragma unroll
    for (int j = 0; j < 5; ++j) zv[j] = accB[j] + zp[p * ZROW + o * 5 + j];
    double s = zv[0] + zv[1] + zv[2] + zv[3] + zv[4];
#pragma unroll
    for (int off = 1; off < 64; off <<= 1) s += __shfl_xor(s, off, 64);
    if (lane == 0) redB[p][0][o >> 6] = s;
  }
  __syncthreads();
  double muB = 0.0;
  if (h == 0) {
    muB = (redB[p][0][0] + redB[p][0][1]) * (1.0 / 640.0);
    double sq = 0.0;
#pragma unroll
    for (int j = 0; j < 5; ++j) { double d = zv[j] - muB; sq = fma(d, d, sq); }
#pragma unroll
    for (int off = 1; off < 64; off <<= 1) sq += __shfl_xor(sq, off, 64);
    if (lane == 0) redB[p][1][o >> 6] = sq;
  }
  __syncthreads();
  if (h == 0) {
    const double rstdB =
        1.0 / sqrt((redB[p][1][0] + redB[p][1][1]) * (1.0 / 640.0) + 1e-5);
    const double gam = (double)fg[o], bet = (double)fb[o];
    double* zo = z_out + (P0 + p) * ZROW + o * 5;
#pragma unroll
    for (int j = 0; j < 5; ++j)
      zo[j] = (zv[j] - muB) * rstdB * gam + bet;
  }
}

// ---------------------------------------------------------------------------
// Kernel 2: LIF1 -> 5x5 mix -> GN(V,T) -> LIF2 -> EMA gate -> dyn LIF -> out
// fp64 state; m overwrites z in place (each lane only touches its own slot).
// ---------------------------------------------------------------------------
__global__ __launch_bounds__(256) void k_temporal(
    const float* __restrict__ x, double* __restrict__ zm,
    const float* __restrict__ la, const float* __restrict__ nm,
    const float* __restrict__ adj, const float* __restrict__ mg,
    const float* __restrict__ mb, float* __restrict__ out)
{
  const int gid = blockIdx.x * 256 + threadIdx.x;
  const int bc = gid >> 3;
  const int u  = gid & 7;
  const bool act = (u < 5);

  double w[5];
#pragma unroll
  for (int v = 0; v < 5; ++v) {
    if (act) {
      double sa = 0.5 * ((double)adj[u * 5 + v] + (double)adj[v * 5 + u]);
      w[v] = (double)nm[u * 5 + v] * (1.0 / (1.0 + exp(-sa)));
    } else {
      w[v] = 0.0;
    }
  }
  const double aa  = 1.0 / (1.0 + exp(-(double)la[0]));
  const double oma = 1.0 - aa;
  const int lane  = threadIdx.x & 63;
  const int gbase = lane & ~7;
  const size_t zoff = (size_t)bc * 5 + u;

  // pass 1: LIF1 + node mix; m overwrites z; accumulate sum(m)
  double v1 = 0.0, ssum = 0.0;
  for (int t = 0; t < T_; ++t) {
    double zvv = act ? zm[(size_t)t * ZSTRIDE + zoff] : 0.0;
    v1 = v1 + (zvv - v1) * 0.5;
    double sp = (v1 - 0.8 >= 0.0) ? 1.0 : 0.0;
    v1 *= (1.0 - sp);
    double m = 0.0;
#pragma unroll
    for (int v = 0; v < 5; ++v) m = fma(w[v], __shfl(sp, gbase + v, 64), m);
    ssum += m;
    if (act) zm[(size_t)t * ZSTRIDE + zoff] = m;
  }
#pragma unroll
  for (int off = 1; off < 8; off <<= 1) ssum += __shfl_xor(ssum, off, 64);
  const double mu = ssum * (1.0 / 640.0);

  // pass 2: two-pass variance over (V,T) = 640
  double sq = 0.0;
  for (int t = 0; t < T_; ++t) {
    if (act) {
      double d = zm[(size_t)t * ZSTRIDE + zoff] - mu;
      sq = fma(d, d, sq);
    }
  }
#pragma unroll
  for (int off = 1; off < 8; off <<= 1) sq += __shfl_xor(sq, off, 64);
  const double rstd = 1.0 / sqrt(sq * (1.0 / 640.0) + 1e-5);
  const double gam = act ? (double)mg[u] : 0.0;
  const double bet = act ? (double)mb[u] : 0.0;

  // pass 3: GN affine + LIF2 + EMA gate + dynamic LIF + clipped output
  double v2 = 0.0, e0 = 0.0, e1 = 0.0, dd0 = 0.0, dd1 = 0.0;
  const size_t xoff = (size_t)bc * 10;
  for (int t = 0; t < T_; ++t) {
    double mval = act ? zm[(size_t)t * ZSTRIDE + zoff] : 0.0;
    double mn = (mval - mu) * rstd * gam + bet;
    v2 = v2 + (mn - v2) * 0.5;
    double s2 = (v2 - 0.8 >= 0.0) ? 1.0 : 0.0;
    v2 *= (1.0 - s2);

    float x0f = 0.f, x1f = 0.f;
    if (act) {
      x0f = x[(size_t)t * XSTRIDE + xoff + u];
      x1f = x[(size_t)t * XSTRIDE + xoff + u + 5];
    }
    e0 = e0 * aa + (double)x0f * oma;
    e1 = e1 * aa + (double)x1f * oma;

    dd0 = dd0 * 0.8 + s2;
    double sd0 = (dd0 - 0.8 * (2.0 - e0) >= 0.0) ? 1.0 : 0.0;
    dd0 *= (1.0 - sd0);

    dd1 = dd1 * 0.8 + s2;
    double sd1 = (dd1 - 0.8 * (2.0 - e1) >= 0.0) ? 1.0 : 0.0;
    dd1 *= (1.0 - sd1);

    if (act) {
      out[(size_t)t * XSTRIDE + xoff + u] =
          fminf(fmaxf(x0f + (float)sd0, 0.f), 1.f);
      out[(size_t)t * XSTRIDE + xoff + u + 5] =
          fminf(fmaxf(x1f + (float)sd1, 0.f), 1.f);
    }
  }
}

// ---------------------------------------------------------------------------
extern "C" void kernel_launch(void* const* d_in, const int* in_sizes, int n_in,
                              void* d_out, int out_size, void* d_ws, size_t ws_size,
                              hipStream_t stream) {
  const float* x   = (const float*)d_in[0];
  const float* W1  = (const float*)d_in[1];
  const float* g1  = (const float*)d_in[2];
  const float* b1  = (const float*)d_in[3];
  const float* la  = (const float*)d_in[4];
  const float* Wf  = (const float*)d_in[5];
  const float* fg  = (const float*)d_in[6];
  const float* fb  = (const float*)d_in[7];
  const float* nm  = (const float*)d_in[8];
  const float* adj = (const float*)d_in[9];
  const float* mg  = (const float*)d_in[10];
  const float* mb  = (const float*)d_in[11];
  float* outp = (float*)d_out;

  double* z_ws = (double*)d_ws;                       // 10,485,760 doubles (84 MB)
  float*  WfT  = (float*)((char*)d_ws + (size_t)T_ * B_ * ZROW * sizeof(double));

  hipLaunchKernelGGL(k_twf,      dim3(128),  dim3(256), 0, stream, Wf, WfT);
  hipLaunchKernelGGL(k_front,    dim3(8192), dim3(512), 0, stream,
                     x, W1, g1, b1, WfT, fg, fb, z_ws);
  hipLaunchKernelGGL(k_temporal, dim3(512),  dim3(256), 0, stream,
                     x, z_ws, la, nm, adj, mg, mb, outp);
}

// Round 5
// 831.728 us; speedup vs baseline: 1.2640x; 1.2640x over previous
//
#include <hip/hip_runtime.h>

#define T_ 128
#define B_ 128
#define C_ 128
#define N_ 10
#define V_ 5
#define XROW 1280            // C_*N_ floats per (t,b)
#define ZROW 640             // C_*V_ per (t,b)
#define ZSTRIDE 81920        // B_*C_*V_ per t
#define XSTRIDE 163840       // B_*C_*N_ per t
#define TQ 32                // t-chunk (T_/4)
#define PAIRS_Q 4096         // pairs per chunk (TQ*B_)

// ---------------------------------------------------------------------------
// k_prep: W1 -> W1d[c][o] fp64 ; Wf -> WfTd[c2][o] fp64   (384 KB total)
// ---------------------------------------------------------------------------
__global__ __launch_bounds__(256) void k_prep(const float* __restrict__ W1,
                                              const float* __restrict__ Wf,
                                              double* __restrict__ W1d,
                                              double* __restrict__ WfTd) {
  int i = blockIdx.x * 256 + threadIdx.x;      // 49152 threads
  if (i < 16384) {
    int c = i >> 7, o = i & 127;
    W1d[i] = (double)W1[o * 128 + c];
  } else if (i < 49152) {
    int k = i - 16384;
    int c2 = k >> 7, o = k & 127;
    WfTd[k] = (double)Wf[o * 256 + c2];
  }
}

// ---------------------------------------------------------------------------
// k_gemm1: y_buf[plocal][o][n] = GN8( W1 @ x[pair] )  (fp64), one t-chunk.
// Block 256 = 2 groups x 128 o-threads; each group handles 2 pairs.
// Weights: per-lane coalesced global (L2).  x: wave-uniform -> s_load + cvt.
// ---------------------------------------------------------------------------
__global__ __launch_bounds__(256) void k_gemm1(
    const float* __restrict__ x, const double* __restrict__ W1d,
    const float* __restrict__ g1, const float* __restrict__ b1,
    double* __restrict__ y_buf, int chunk_base)
{
  const int tid = threadIdx.x;
  const int o   = tid & 127;
  const int g2  = tid >> 7;                    // group 0/1
  const int plA = blockIdx.x * 4 + g2 * 2;     // chunk-local pair indices
  const int plB = plA + 1;
  const int pgA = chunk_base + plA;            // global pair indices
  const int pgB = chunk_base + plB;

  const int xbA = __builtin_amdgcn_readfirstlane(pgA * XROW);
  const int xbB = __builtin_amdgcn_readfirstlane(pgB * XROW);

  double accA[10], accB[10];
#pragma unroll
  for (int j = 0; j < 10; ++j) { accA[j] = 0.0; accB[j] = 0.0; }

#pragma unroll 2
  for (int c = 0; c < 128; ++c) {
    const double w = W1d[(c << 7) + o];        // per-lane, coalesced, L2-hot
#pragma unroll
    for (int j = 0; j < 10; ++j) {
      accA[j] = fma(w, (double)x[xbA + c * 10 + j], accA[j]);
      accB[j] = fma(w, (double)x[xbB + c * 10 + j], accB[j]);
    }
  }

  // GN8 per pair: group = (o>>4), 16 lanes x 10 = 160 elems, all in-wave
  const double gam = (double)g1[o], bet = (double)b1[o];
#pragma unroll
  for (int P = 0; P < 2; ++P) {
    double* acc = P ? accB : accA;
    double s = 0.0;
#pragma unroll
    for (int j = 0; j < 10; ++j) s += acc[j];
#pragma unroll
    for (int off = 1; off < 16; off <<= 1) s += __shfl_xor(s, off, 64);
    const double mu = s * (1.0 / 160.0);
    double sq = 0.0;
#pragma unroll
    for (int j = 0; j < 10; ++j) { double d = acc[j] - mu; sq = fma(d, d, sq); }
#pragma unroll
    for (int off = 1; off < 16; off <<= 1) sq += __shfl_xor(sq, off, 64);
    const double rstd = 1.0 / sqrt(sq * (1.0 / 160.0) + 1e-5);
    double* yo = y_buf + (size_t)(P ? plB : plA) * XROW + o * 10;
#pragma unroll
    for (int j = 0; j < 10; ++j) yo[j] = (acc[j] - mu) * rstd * gam + bet;
  }
}

// ---------------------------------------------------------------------------
// k_gemm2: z[pair][o][v] = GN1( Wf @ [y|y'] ), one t-chunk.
// y: wave-uniform fp64 -> s_load (no cvt).  WfTd: per-lane coalesced.
// ---------------------------------------------------------------------------
__global__ __launch_bounds__(256) void k_gemm2(
    const double* __restrict__ y_buf, const double* __restrict__ WfTd,
    const float* __restrict__ fg, const float* __restrict__ fb,
    double* __restrict__ z_out, int chunk_base)
{
  __shared__ double red[2][2][2][2];           // [group][pair][stat][wave]
  const int tid  = threadIdx.x;
  const int o    = tid & 127;
  const int g2   = tid >> 7;
  const int wv   = (tid >> 6) & 1;
  const int lane = tid & 63;
  const int plA  = blockIdx.x * 4 + g2 * 2;
  const int plB  = plA + 1;

  const int ybA = __builtin_amdgcn_readfirstlane(plA * XROW);
  const int ybB = __builtin_amdgcn_readfirstlane(plB * XROW);

  double accA[5], accB[5];
#pragma unroll
  for (int v = 0; v < 5; ++v) { accA[v] = 0.0; accB[v] = 0.0; }

#pragma unroll 2
  for (int c = 0; c < 128; ++c) {
    const double wa = WfTd[(c << 7) + o];
    const double wb = WfTd[((c + 128) << 7) + o];
#pragma unroll
    for (int v = 0; v < 5; ++v) {
      accA[v] = fma(wa, y_buf[ybA + c * 10 + v], accA[v]);
      accA[v] = fma(wb, y_buf[ybA + c * 10 + 5 + v], accA[v]);
      accB[v] = fma(wa, y_buf[ybB + c * 10 + v], accB[v]);
      accB[v] = fma(wb, y_buf[ybB + c * 10 + 5 + v], accB[v]);
    }
  }

  // GN1 over 640 values per pair (2 waves per group share a pair set)
  double s0 = accA[0] + accA[1] + accA[2] + accA[3] + accA[4];
  double s1 = accB[0] + accB[1] + accB[2] + accB[3] + accB[4];
#pragma unroll
  for (int off = 1; off < 64; off <<= 1) {
    s0 += __shfl_xor(s0, off, 64);
    s1 += __shfl_xor(s1, off, 64);
  }
  if (lane == 0) { red[g2][0][0][wv] = s0; red[g2][1][0][wv] = s1; }
  __syncthreads();
  const double mu0 = (red[g2][0][0][0] + red[g2][0][0][1]) * (1.0 / 640.0);
  const double mu1 = (red[g2][1][0][0] + red[g2][1][0][1]) * (1.0 / 640.0);
  double q0 = 0.0, q1 = 0.0;
#pragma unroll
  for (int v = 0; v < 5; ++v) {
    double d0 = accA[v] - mu0; q0 = fma(d0, d0, q0);
    double d1 = accB[v] - mu1; q1 = fma(d1, d1, q1);
  }
#pragma unroll
  for (int off = 1; off < 64; off <<= 1) {
    q0 += __shfl_xor(q0, off, 64);
    q1 += __shfl_xor(q1, off, 64);
  }
  if (lane == 0) { red[g2][0][1][wv] = q0; red[g2][1][1][wv] = q1; }
  __syncthreads();
  const double rstd0 =
      1.0 / sqrt((red[g2][0][1][0] + red[g2][0][1][1]) * (1.0 / 640.0) + 1e-5);
  const double rstd1 =
      1.0 / sqrt((red[g2][1][1][0] + red[g2][1][1][1]) * (1.0 / 640.0) + 1e-5);

  const double gam = (double)fg[o], bet = (double)fb[o];
  double* zoA = z_out + (size_t)(chunk_base + plA) * ZROW + o * 5;
  double* zoB = z_out + (size_t)(chunk_base + plB) * ZROW + o * 5;
#pragma unroll
  for (int v = 0; v < 5; ++v) {
    zoA[v] = (accA[v] - mu0) * rstd0 * gam + bet;
    zoB[v] = (accB[v] - mu1) * rstd1 * gam + bet;
  }
}

// ---------------------------------------------------------------------------
// k_temporal: LIF1 -> 5x5 mix -> GN(V,T) -> LIF2 -> EMA gate -> dyn LIF -> out
// fp64 state; m overwrites z in place; sum+sumsq fused; next-t prefetch.
// ---------------------------------------------------------------------------
__global__ __launch_bounds__(256) void k_temporal(
    const float* __restrict__ x, double* __restrict__ zm,
    const float* __restrict__ la, const float* __restrict__ nm,
    const float* __restrict__ adj, const float* __restrict__ mg,
    const float* __restrict__ mb, float* __restrict__ out)
{
  const int gid = blockIdx.x * 256 + threadIdx.x;
  const int bc = gid >> 3;
  const int u  = gid & 7;
  const bool act = (u < 5);

  double w[5];
#pragma unroll
  for (int v = 0; v < 5; ++v) {
    if (act) {
      double sa = 0.5 * ((double)adj[u * 5 + v] + (double)adj[v * 5 + u]);
      w[v] = (double)nm[u * 5 + v] * (1.0 / (1.0 + exp(-sa)));
    } else {
      w[v] = 0.0;
    }
  }
  const double aa  = 1.0 / (1.0 + exp(-(double)la[0]));
  const double oma = 1.0 - aa;
  const int lane  = threadIdx.x & 63;
  const int gbase = lane & ~7;
  const size_t zoff = (size_t)bc * 5 + u;

  // pass 1: LIF1 + node mix; m overwrites z; fused sum & sumsq
  double v1 = 0.0, ssum = 0.0, ssq = 0.0;
  double znext = act ? zm[zoff] : 0.0;
  for (int t = 0; t < T_; ++t) {
    const double zc = znext;
    if (t < T_ - 1)
      znext = act ? zm[zoff + (size_t)(t + 1) * ZSTRIDE] : 0.0;
    v1 = v1 + (zc - v1) * 0.5;
    double sp = (v1 - 0.8 >= 0.0) ? 1.0 : 0.0;
    v1 *= (1.0 - sp);
    double m = 0.0;
#pragma unroll
    for (int v = 0; v < 5; ++v) m = fma(w[v], __shfl(sp, gbase + v, 64), m);
    ssum += m;
    ssq = fma(m, m, ssq);
    if (act) zm[zoff + (size_t)t * ZSTRIDE] = m;
  }
#pragma unroll
  for (int off = 1; off < 8; off <<= 1) {
    ssum += __shfl_xor(ssum, off, 64);
    ssq  += __shfl_xor(ssq,  off, 64);
  }
  const double mu = ssum * (1.0 / 640.0);
  double var = ssq * (1.0 / 640.0) - mu * mu;
  const double rstd = 1.0 / sqrt(var + 1e-5);
  const double gam = act ? (double)mg[u] : 0.0;
  const double bet = act ? (double)mb[u] : 0.0;

  // pass 2: GN affine + LIF2 + EMA gate + dynamic LIF + clipped output
  double v2 = 0.0, e0 = 0.0, e1 = 0.0, dd0 = 0.0, dd1 = 0.0;
  const size_t xoff = (size_t)bc * 10;
  double mnext = act ? zm[zoff] : 0.0;
  float x0n = act ? x[xoff + u] : 0.f;
  float x1n = act ? x[xoff + u + 5] : 0.f;
  for (int t = 0; t < T_; ++t) {
    const double mval = mnext;
    const float x0f = x0n, x1f = x1n;
    if (t < T_ - 1) {
      mnext = act ? zm[zoff + (size_t)(t + 1) * ZSTRIDE] : 0.0;
      x0n = act ? x[(size_t)(t + 1) * XSTRIDE + xoff + u] : 0.f;
      x1n = act ? x[(size_t)(t + 1) * XSTRIDE + xoff + u + 5] : 0.f;
    }
    double mn = (mval - mu) * rstd * gam + bet;
    v2 = v2 + (mn - v2) * 0.5;
    double s2 = (v2 - 0.8 >= 0.0) ? 1.0 : 0.0;
    v2 *= (1.0 - s2);

    e0 = e0 * aa + (double)x0f * oma;
    e1 = e1 * aa + (double)x1f * oma;

    dd0 = dd0 * 0.8 + s2;
    double sd0 = (dd0 - 0.8 * (2.0 - e0) >= 0.0) ? 1.0 : 0.0;
    dd0 *= (1.0 - sd0);

    dd1 = dd1 * 0.8 + s2;
    double sd1 = (dd1 - 0.8 * (2.0 - e1) >= 0.0) ? 1.0 : 0.0;
    dd1 *= (1.0 - sd1);

    if (act) {
      out[(size_t)t * XSTRIDE + xoff + u] =
          fminf(fmaxf(x0f + (float)sd0, 0.f), 1.f);
      out[(size_t)t * XSTRIDE + xoff + u + 5] =
          fminf(fmaxf(x1f + (float)sd1, 0.f), 1.f);
    }
  }
}

// ---------------------------------------------------------------------------
extern "C" void kernel_launch(void* const* d_in, const int* in_sizes, int n_in,
                              void* d_out, int out_size, void* d_ws, size_t ws_size,
                              hipStream_t stream) {
  const float* x   = (const float*)d_in[0];
  const float* W1  = (const float*)d_in[1];
  const float* g1  = (const float*)d_in[2];
  const float* b1  = (const float*)d_in[3];
  const float* la  = (const float*)d_in[4];
  const float* Wf  = (const float*)d_in[5];
  const float* fg  = (const float*)d_in[6];
  const float* fb  = (const float*)d_in[7];
  const float* nm  = (const float*)d_in[8];
  const float* adj = (const float*)d_in[9];
  const float* mg  = (const float*)d_in[10];
  const float* mb  = (const float*)d_in[11];
  float* outp = (float*)d_out;

  // ws layout (fp64): z 83886080 B | y_buf 41943040 B | W1d 131072 B | WfTd 262144 B
  double* z_ws  = (double*)d_ws;
  double* y_buf = (double*)((char*)d_ws + 83886080);
  double* W1d   = (double*)((char*)d_ws + 83886080 + 41943040);
  double* WfTd  = (double*)((char*)d_ws + 83886080 + 41943040 + 131072);

  hipLaunchKernelGGL(k_prep, dim3(192), dim3(256), 0, stream, W1, Wf, W1d, WfTd);
  for (int q = 0; q < 4; ++q) {
    const int cb = q * PAIRS_Q;
    hipLaunchKernelGGL(k_gemm1, dim3(PAIRS_Q / 4), dim3(256), 0, stream,
                       x, W1d, g1, b1, y_buf, cb);
    hipLaunchKernelGGL(k_gemm2, dim3(PAIRS_Q / 4), dim3(256), 0, stream,
                       y_buf, WfTd, fg, fb, z_ws, cb);
  }
  hipLaunchKernelGGL(k_temporal, dim3(512), dim3(256), 0, stream,
                     x, z_ws, la, nm, adj, mg, mb, outp);
}